// Round 1
// baseline (402.315 us; speedup 1.0000x reference)
//
#include <hip/hip_runtime.h>
#include <math.h>

#define N_NODES 25000
#define N_EDGES 400000
#define EMBED   128
#define HEADS   8
#define DK      16

// ---------------------------------------------------------------------------
// GEMM: C[m][j] = sum_k A[m][k] * W[j][k] + bias[j]   (i.e. A @ W^T + b)
// M arbitrary, K = 128 (chunked by 64 in LDS), 128 cols in grid.y tiles of 64.
// k-major LDS (stride 72 floats): 16B-aligned ds_read_b128 in microkernel;
// staging writes are 4-way bank conflicted (1.58x) but staging is small.
// ---------------------------------------------------------------------------
#define LSTR 72

__global__ __launch_bounds__(256) void gemm_xwT(
    const float* __restrict__ A, const float* __restrict__ W,
    const float* __restrict__ bias, float* __restrict__ C, int M)
{
    __shared__ float As[64 * LSTR];   // [k][row]
    __shared__ float Bs[64 * LSTR];   // [k][col]
    const int t  = threadIdx.x;
    const int tx = t & 15, ty = t >> 4;
    const int m0 = blockIdx.x * 64;
    const int c0 = blockIdx.y * 64;

    float acc[16];
#pragma unroll
    for (int i = 0; i < 16; ++i) acc[i] = 0.f;

    for (int kc = 0; kc < 2; ++kc) {
        // stage 64 rows x 64 k (A) and 64 cols x 64 k (W), k-major
#pragma unroll
        for (int iter = 0; iter < 16; ++iter) {
            int id = iter * 256 + t;
            int k = id & 63, r = id >> 6;
            int row = m0 + r;
            float av = (row < M) ? A[row * 128 + kc * 64 + k] : 0.0f;
            As[k * LSTR + r] = av;
            Bs[k * LSTR + r] = W[(c0 + r) * 128 + kc * 64 + k];
        }
        __syncthreads();

#pragma unroll 8
        for (int k = 0; k < 64; ++k) {
            float4 a = *reinterpret_cast<const float4*>(&As[k * LSTR + ty * 4]);
            float4 b = *reinterpret_cast<const float4*>(&Bs[k * LSTR + tx * 4]);
            acc[0]  += a.x * b.x; acc[1]  += a.x * b.y; acc[2]  += a.x * b.z; acc[3]  += a.x * b.w;
            acc[4]  += a.y * b.x; acc[5]  += a.y * b.y; acc[6]  += a.y * b.z; acc[7]  += a.y * b.w;
            acc[8]  += a.z * b.x; acc[9]  += a.z * b.y; acc[10] += a.z * b.z; acc[11] += a.z * b.w;
            acc[12] += a.w * b.x; acc[13] += a.w * b.y; acc[14] += a.w * b.z; acc[15] += a.w * b.w;
        }
        __syncthreads();
    }

#pragma unroll
    for (int i = 0; i < 4; ++i) {
        int row = m0 + ty * 4 + i;
        if (row >= M) continue;
#pragma unroll
        for (int j = 0; j < 4; ++j) {
            int col = c0 + tx * 4 + j;
            C[row * 128 + col] = acc[i * 4 + j] + bias[col];
        }
    }
}

// ---------------------------------------------------------------------------
// Per-edge logits: logits[e][h] = 0.25 * dot(Q[dst,h*16:+16], K[src,...]) + bias
// Also builds the degree histogram (one atomic per edge).
// ---------------------------------------------------------------------------
__global__ __launch_bounds__(256) void edge_logits(
    const float* __restrict__ Q, const float* __restrict__ K,
    const int* __restrict__ ei, const float* __restrict__ attn_bias,
    float* __restrict__ logits, int* __restrict__ deg)
{
    int t = blockIdx.x * 256 + threadIdx.x;
    int e = t >> 3, h = t & 7;
    if (e >= N_EDGES) return;
    int dst = ei[e];
    int src = ei[N_EDGES + e];
    const float4* qp = reinterpret_cast<const float4*>(Q + dst * 128 + h * 16);
    const float4* kp = reinterpret_cast<const float4*>(K + src * 128 + h * 16);
    float s = 0.f;
#pragma unroll
    for (int i = 0; i < 4; ++i) {
        float4 q4 = qp[i], k4 = kp[i];
        s += q4.x * k4.x + q4.y * k4.y + q4.z * k4.z + q4.w * k4.w;
    }
    logits[e * 8 + h] = 0.25f * s + attn_bias[e * 8 + h];
    if (h == 0) atomicAdd(&deg[dst], 1);
}

// ---------------------------------------------------------------------------
// Exclusive scan of deg -> offsets (and cursor copy). Single block.
// ---------------------------------------------------------------------------
__global__ __launch_bounds__(256) void scan_offsets(
    const int* __restrict__ deg, int* __restrict__ offsets,
    int* __restrict__ cursor)
{
    __shared__ int part[256];
    int t = threadIdx.x;
    int start = t * 98;
    int end = start + 98; if (end > N_NODES) end = N_NODES;
    if (start > N_NODES) start = N_NODES;
    int s = 0;
    for (int i = start; i < end; ++i) s += deg[i];
    part[t] = s;
    __syncthreads();
    for (int off = 1; off < 256; off <<= 1) {
        int v = (t >= off) ? part[t - off] : 0;
        __syncthreads();
        part[t] += v;
        __syncthreads();
    }
    int run = part[t] - s;  // exclusive prefix of this thread's chunk
    for (int i = start; i < end; ++i) {
        offsets[i] = run;
        cursor[i] = run;
        run += deg[i];
    }
    if (t == 0) offsets[N_NODES] = N_EDGES;
}

__global__ __launch_bounds__(256) void scatter_edges(
    const int* __restrict__ ei, int* __restrict__ cursor,
    int* __restrict__ csr)
{
    int e = blockIdx.x * 256 + threadIdx.x;
    if (e >= N_EDGES) return;
    int pos = atomicAdd(&cursor[ei[e]], 1);
    csr[pos] = e;
}

// ---------------------------------------------------------------------------
// One wave per node: segment softmax + weighted V aggregation.
// Phase A: per-head max & sum-exp via butterfly shuffles (no LDS).
// Phase B: lane -> output dim (lane and lane+64); p recomputed on the fly.
// ---------------------------------------------------------------------------
__global__ __launch_bounds__(256) void node_attn(
    const float* __restrict__ logits, const float* __restrict__ V,
    const int* __restrict__ ei, const int* __restrict__ offsets,
    const int* __restrict__ csr, float* __restrict__ agg)
{
    int lane = threadIdx.x & 63;
    int wid  = threadIdx.x >> 6;
    int n = blockIdx.x * 4 + wid;
    int start = offsets[n], end = offsets[n + 1];

    float m[8];
#pragma unroll
    for (int h = 0; h < 8; ++h) m[h] = -INFINITY;
    for (int i = start + lane; i < end; i += 64) {
        int eid = csr[i];
        const float4* lp = reinterpret_cast<const float4*>(logits + eid * 8);
        float4 l0 = lp[0], l1 = lp[1];
        m[0] = fmaxf(m[0], l0.x); m[1] = fmaxf(m[1], l0.y);
        m[2] = fmaxf(m[2], l0.z); m[3] = fmaxf(m[3], l0.w);
        m[4] = fmaxf(m[4], l1.x); m[5] = fmaxf(m[5], l1.y);
        m[6] = fmaxf(m[6], l1.z); m[7] = fmaxf(m[7], l1.w);
    }
#pragma unroll
    for (int h = 0; h < 8; ++h) {
#pragma unroll
        for (int off = 32; off; off >>= 1)
            m[h] = fmaxf(m[h], __shfl_xor(m[h], off, 64));
    }

    float z[8];
#pragma unroll
    for (int h = 0; h < 8; ++h) z[h] = 0.f;
    for (int i = start + lane; i < end; i += 64) {
        int eid = csr[i];
        const float4* lp = reinterpret_cast<const float4*>(logits + eid * 8);
        float4 l0 = lp[0], l1 = lp[1];
        z[0] += __expf(l0.x - m[0]); z[1] += __expf(l0.y - m[1]);
        z[2] += __expf(l0.z - m[2]); z[3] += __expf(l0.w - m[3]);
        z[4] += __expf(l1.x - m[4]); z[5] += __expf(l1.y - m[5]);
        z[6] += __expf(l1.z - m[6]); z[7] += __expf(l1.w - m[7]);
    }
#pragma unroll
    for (int h = 0; h < 8; ++h) {
#pragma unroll
        for (int off = 32; off; off >>= 1)
            z[h] += __shfl_xor(z[h], off, 64);
    }

    // lane covers output dims `lane` (head h0) and `lane+64` (head h0+4)
    int h0 = lane >> 4;
    float mA = (h0 == 0) ? m[0] : (h0 == 1) ? m[1] : (h0 == 2) ? m[2] : m[3];
    float mB = (h0 == 0) ? m[4] : (h0 == 1) ? m[5] : (h0 == 2) ? m[6] : m[7];
    float zA = (h0 == 0) ? z[0] : (h0 == 1) ? z[1] : (h0 == 2) ? z[2] : z[3];
    float zB = (h0 == 0) ? z[4] : (h0 == 1) ? z[5] : (h0 == 2) ? z[6] : z[7];
    float invA = (zA > 0.f) ? 1.f / zA : 0.f;
    float invB = (zB > 0.f) ? 1.f / zB : 0.f;

    float acc0 = 0.f, acc1 = 0.f;
    for (int i = start; i < end; ++i) {
        int eid = csr[i];                       // wave-uniform -> broadcast load
        int src = ei[N_EDGES + eid];
        float la = logits[eid * 8 + h0];
        float lb = logits[eid * 8 + h0 + 4];
        float pa = __expf(la - mA);
        float pb = __expf(lb - mB);
        acc0 += pa * V[src * 128 + lane];
        acc1 += pb * V[src * 128 + 64 + lane];
    }
    agg[n * 128 + lane]      = acc0 * invA;
    agg[n * 128 + 64 + lane] = acc1 * invB;
}

// ---------------------------------------------------------------------------
extern "C" void kernel_launch(void* const* d_in, const int* in_sizes, int n_in,
                              void* d_out, int out_size, void* d_ws, size_t ws_size,
                              hipStream_t stream)
{
    const float* x         = (const float*)d_in[0];
    const int*   ei        = (const int*)  d_in[1];
    const float* attn_bias = (const float*)d_in[2];
    const float* Wq = (const float*)d_in[3];
    const float* bq = (const float*)d_in[4];
    const float* Wk = (const float*)d_in[5];
    const float* bk = (const float*)d_in[6];
    const float* Wv = (const float*)d_in[7];
    const float* bv = (const float*)d_in[8];
    const float* Wo = (const float*)d_in[9];
    const float* bo = (const float*)d_in[10];

    float* out    = (float*)d_out;                // [N,128]
    float* logits = out + N_NODES * EMBED;        // [E,8] (output 1)

    float* Q   = (float*)d_ws;
    float* K   = Q + N_NODES * EMBED;
    float* V   = K + N_NODES * EMBED;
    float* AGG = V + N_NODES * EMBED;
    int* deg     = (int*)(AGG + N_NODES * EMBED);
    int* offsets = deg + N_NODES;                 // N+1
    int* cursor  = offsets + N_NODES + 1;
    int* csr     = cursor + N_NODES;              // E

    hipMemsetAsync(deg, 0, N_NODES * sizeof(int), stream);

    dim3 ggrid((N_NODES + 63) / 64, 2);
    gemm_xwT<<<ggrid, 256, 0, stream>>>(x, Wq, bq, Q, N_NODES);
    gemm_xwT<<<ggrid, 256, 0, stream>>>(x, Wk, bk, K, N_NODES);
    gemm_xwT<<<ggrid, 256, 0, stream>>>(x, Wv, bv, V, N_NODES);

    edge_logits<<<(N_EDGES * 8) / 256, 256, 0, stream>>>(Q, K, ei, attn_bias, logits, deg);
    scan_offsets<<<1, 256, 0, stream>>>(deg, offsets, cursor);
    scatter_edges<<<(N_EDGES + 255) / 256, 256, 0, stream>>>(ei, cursor, csr);
    node_attn<<<N_NODES / 4, 256, 0, stream>>>(logits, V, ei, offsets, csr, AGG);

    gemm_xwT<<<ggrid, 256, 0, stream>>>(AGG, Wo, bo, out, N_NODES);
}

// Round 2
// 392.956 us; speedup vs baseline: 1.0238x; 1.0238x over previous
//
#include <hip/hip_runtime.h>
#include <math.h>

#define N_NODES 25000
#define N_EDGES 400000
#define EMBED   128
#define HEADS   8
#define DK      16

// ---------------------------------------------------------------------------
// GEMM: C[m][j] = sum_k A[m][k] * W[j][k] + bias[j]   (i.e. A @ W^T + b)
// ---------------------------------------------------------------------------
#define LSTR 72

__global__ __launch_bounds__(256) void gemm_xwT(
    const float* __restrict__ A, const float* __restrict__ W,
    const float* __restrict__ bias, float* __restrict__ C, int M)
{
    __shared__ float As[64 * LSTR];   // [k][row]
    __shared__ float Bs[64 * LSTR];   // [k][col]
    const int t  = threadIdx.x;
    const int tx = t & 15, ty = t >> 4;
    const int m0 = blockIdx.x * 64;
    const int c0 = blockIdx.y * 64;

    float acc[16];
#pragma unroll
    for (int i = 0; i < 16; ++i) acc[i] = 0.f;

    for (int kc = 0; kc < 2; ++kc) {
#pragma unroll
        for (int iter = 0; iter < 16; ++iter) {
            int id = iter * 256 + t;
            int k = id & 63, r = id >> 6;
            int row = m0 + r;
            float av = (row < M) ? A[row * 128 + kc * 64 + k] : 0.0f;
            As[k * LSTR + r] = av;
            Bs[k * LSTR + r] = W[(c0 + r) * 128 + kc * 64 + k];
        }
        __syncthreads();

#pragma unroll 8
        for (int k = 0; k < 64; ++k) {
            float4 a = *reinterpret_cast<const float4*>(&As[k * LSTR + ty * 4]);
            float4 b = *reinterpret_cast<const float4*>(&Bs[k * LSTR + tx * 4]);
            acc[0]  += a.x * b.x; acc[1]  += a.x * b.y; acc[2]  += a.x * b.z; acc[3]  += a.x * b.w;
            acc[4]  += a.y * b.x; acc[5]  += a.y * b.y; acc[6]  += a.y * b.z; acc[7]  += a.y * b.w;
            acc[8]  += a.z * b.x; acc[9]  += a.z * b.y; acc[10] += a.z * b.z; acc[11] += a.z * b.w;
            acc[12] += a.w * b.x; acc[13] += a.w * b.y; acc[14] += a.w * b.z; acc[15] += a.w * b.w;
        }
        __syncthreads();
    }

#pragma unroll
    for (int i = 0; i < 4; ++i) {
        int row = m0 + ty * 4 + i;
        if (row >= M) continue;
#pragma unroll
        for (int j = 0; j < 4; ++j) {
            int col = c0 + tx * 4 + j;
            C[row * 128 + col] = acc[i * 4 + j] + bias[col];
        }
    }
}

// ---------------------------------------------------------------------------
// CSR build: degree histogram, exclusive scan, scatter.
// ---------------------------------------------------------------------------
__global__ __launch_bounds__(256) void build_deg(
    const int* __restrict__ ei, int* __restrict__ deg)
{
    int e = blockIdx.x * 256 + threadIdx.x;
    if (e < N_EDGES) atomicAdd(&deg[ei[e]], 1);
}

__global__ __launch_bounds__(256) void scan_offsets(
    const int* __restrict__ deg, int* __restrict__ offsets,
    int* __restrict__ cursor)
{
    __shared__ int part[256];
    int t = threadIdx.x;
    int start = t * 98;
    int end = start + 98; if (end > N_NODES) end = N_NODES;
    if (start > N_NODES) start = N_NODES;
    int s = 0;
    for (int i = start; i < end; ++i) s += deg[i];
    part[t] = s;
    __syncthreads();
    for (int off = 1; off < 256; off <<= 1) {
        int v = (t >= off) ? part[t - off] : 0;
        __syncthreads();
        part[t] += v;
        __syncthreads();
    }
    int run = part[t] - s;
    for (int i = start; i < end; ++i) {
        offsets[i] = run;
        cursor[i] = run;
        run += deg[i];
    }
    if (t == 0) offsets[N_NODES] = N_EDGES;
}

__global__ __launch_bounds__(256) void scatter_edges(
    const int* __restrict__ ei, int* __restrict__ cursor,
    int* __restrict__ csr)
{
    int e = blockIdx.x * 256 + threadIdx.x;
    if (e >= N_EDGES) return;
    int pos = atomicAdd(&cursor[ei[e]], 1);
    csr[pos] = e;
}

// ---------------------------------------------------------------------------
// Fused per-node kernel: logits + softmax + V aggregation in ONE edge pass.
// One wave per node. Lane l covers dims l and l+64.
// 16-lane group g computes head g (dims 0-63 half) and head g+4 (dims 64-127).
// exp without max-subtraction: e^l / sum e^l == e^(l-m)/sum e^(l-m); logits
// are O(±10), safely inside fp32 exp range.
// ---------------------------------------------------------------------------
__global__ __launch_bounds__(256) void fused_attn(
    const float* __restrict__ Q, const float* __restrict__ K,
    const float* __restrict__ V, const int* __restrict__ ei,
    const float* __restrict__ attn_bias,
    const int* __restrict__ offsets, const int* __restrict__ csr,
    float* __restrict__ logits, float* __restrict__ agg)
{
    int lane = threadIdx.x & 63;
    int wid  = threadIdx.x >> 6;
    int n = blockIdx.x * 4 + wid;
    int start = offsets[n], end = offsets[n + 1];
    int g = lane >> 4;   // head group

    float q0 = Q[n * 128 + lane];
    float q1 = Q[n * 128 + 64 + lane];

    float z0 = 0.f, z1 = 0.f, acc0 = 0.f, acc1 = 0.f;

    for (int i = start; i < end; ++i) {
        int eid = csr[i];                 // wave-uniform
        int src = ei[N_EDGES + eid];
        float k0 = K[src * 128 + lane];
        float k1 = K[src * 128 + 64 + lane];
        float v0 = V[src * 128 + lane];
        float v1 = V[src * 128 + 64 + lane];
        float s0 = q0 * k0, s1 = q1 * k1;
#pragma unroll
        for (int off = 1; off < 16; off <<= 1) {
            s0 += __shfl_xor(s0, off, 64);
            s1 += __shfl_xor(s1, off, 64);
        }
        float l0 = 0.25f * s0 + attn_bias[eid * 8 + g];
        float l1 = 0.25f * s1 + attn_bias[eid * 8 + 4 + g];
        if ((lane & 15) == 0) {
            logits[eid * 8 + g]     = l0;
            logits[eid * 8 + 4 + g] = l1;
        }
        float p0 = __expf(l0);
        float p1 = __expf(l1);
        z0 += p0; z1 += p1;              // replicated within group
        acc0 += p0 * v0;
        acc1 += p1 * v1;
    }

    float inv0 = (z0 > 0.f) ? 1.f / z0 : 0.f;
    float inv1 = (z1 > 0.f) ? 1.f / z1 : 0.f;
    agg[n * 128 + lane]      = acc0 * inv0;
    agg[n * 128 + 64 + lane] = acc1 * inv1;
}

// ---------------------------------------------------------------------------
extern "C" void kernel_launch(void* const* d_in, const int* in_sizes, int n_in,
                              void* d_out, int out_size, void* d_ws, size_t ws_size,
                              hipStream_t stream)
{
    const float* x         = (const float*)d_in[0];
    const int*   ei        = (const int*)  d_in[1];
    const float* attn_bias = (const float*)d_in[2];
    const float* Wq = (const float*)d_in[3];
    const float* bq = (const float*)d_in[4];
    const float* Wk = (const float*)d_in[5];
    const float* bk = (const float*)d_in[6];
    const float* Wv = (const float*)d_in[7];
    const float* bv = (const float*)d_in[8];
    const float* Wo = (const float*)d_in[9];
    const float* bo = (const float*)d_in[10];

    float* out    = (float*)d_out;                // [N,128]
    float* logits = out + N_NODES * EMBED;        // [E,8] (output 1)

    float* Q   = (float*)d_ws;
    float* K   = Q + N_NODES * EMBED;
    float* V   = K + N_NODES * EMBED;
    float* AGG = V + N_NODES * EMBED;
    int* deg     = (int*)(AGG + N_NODES * EMBED);
    int* offsets = deg + N_NODES;                 // N+1
    int* cursor  = offsets + N_NODES + 1;
    int* csr     = cursor + N_NODES;              // E

    hipMemsetAsync(deg, 0, N_NODES * sizeof(int), stream);

    dim3 ggrid((N_NODES + 63) / 64, 2);
    gemm_xwT<<<ggrid, 256, 0, stream>>>(x, Wq, bq, Q, N_NODES);
    gemm_xwT<<<ggrid, 256, 0, stream>>>(x, Wk, bk, K, N_NODES);
    gemm_xwT<<<ggrid, 256, 0, stream>>>(x, Wv, bv, V, N_NODES);

    build_deg<<<(N_EDGES + 255) / 256, 256, 0, stream>>>(ei, deg);
    scan_offsets<<<1, 256, 0, stream>>>(deg, offsets, cursor);
    scatter_edges<<<(N_EDGES + 255) / 256, 256, 0, stream>>>(ei, cursor, csr);

    fused_attn<<<N_NODES / 4, 256, 0, stream>>>(Q, K, V, ei, attn_bias,
                                                offsets, csr, logits, AGG);

    gemm_xwT<<<ggrid, 256, 0, stream>>>(AGG, Wo, bo, out, N_NODES);
}

// Round 3
// 313.926 us; speedup vs baseline: 1.2816x; 1.2517x over previous
//
#include <hip/hip_runtime.h>
#include <math.h>

#define N_NODES 25000
#define N_EDGES 400000
#define EMBED   128
#define HEADS   8
#define DK      16

typedef __attribute__((ext_vector_type(8))) short bf16x8;
typedef __attribute__((ext_vector_type(4))) float f32x4;
typedef unsigned int uint;
typedef unsigned short ushort;

__device__ inline uint pack2_bf16(float a, float b) {
    union { float f; uint u; } ua, ub;
    ua.f = a; ub.f = b;
    uint ra = (ua.u + 0x7FFFu + ((ua.u >> 16) & 1u)) >> 16;
    uint rb = (ub.u + 0x7FFFu + ((ub.u >> 16) & 1u)) >> 16;
    return (ra & 0xFFFFu) | (rb << 16);
}
__device__ inline ushort cvt_bf16(float a) {
    union { float f; uint u; } ua; ua.f = a;
    return (ushort)((ua.u + 0x7FFFu + ((ua.u >> 16) & 1u)) >> 16);
}
__device__ inline float bf16_lo(uint u) {
    union { uint u; float f; } x; x.u = u << 16; return x.f;
}
__device__ inline float bf16_hi(uint u) {
    union { uint u; float f; } x; x.u = u & 0xFFFF0000u; return x.f;
}

// ---------------------------------------------------------------------------
// Convert x (N*128) and the four 128x128 weights to bf16, pairwise.
// ---------------------------------------------------------------------------
#define NX (N_NODES * 128)
__global__ __launch_bounds__(256) void convert_all(
    const float* __restrict__ x,
    const float* __restrict__ Wq, const float* __restrict__ Wk,
    const float* __restrict__ Wv, const float* __restrict__ Wo,
    ushort* __restrict__ xb, ushort* __restrict__ wb)
{
    int i = blockIdx.x * 256 + threadIdx.x;   // pair index
    int base = i * 2;
    if (base < NX) {
        float2 v = *reinterpret_cast<const float2*>(x + base);
        reinterpret_cast<uint*>(xb)[i] = pack2_bf16(v.x, v.y);
    } else {
        int j = base - NX;
        if (j < 4 * 16384) {
            const float* src = (j < 16384) ? Wq + j
                             : (j < 32768) ? Wk + (j - 16384)
                             : (j < 49152) ? Wv + (j - 32768)
                             :               Wo + (j - 49152);
            float2 v = *reinterpret_cast<const float2*>(src);
            reinterpret_cast<uint*>(wb)[j >> 1] = pack2_bf16(v.x, v.y);
        }
    }
}

// ---------------------------------------------------------------------------
// MFMA GEMM: C[m][n] = sum_k A[m][k] * W[n][k] + bias[n]
// A: [M,128] bf16 row-major. W: [128,128] bf16 row-major. K=128.
// Block = 4 waves, 64 rows; wave handles 16 rows x 128 cols (8 col tiles).
// A frag: lane holds A[m0+(l&15)][ks + (l>>4)*8 + j]  (16B contiguous load)
// B frag: lane holds W[ct*16+(l&15)][ks + (l>>4)*8 + j]
// C/D:    lane l, reg r -> row (l>>4)*4+r, col l&15   (verified m89/m91)
// ---------------------------------------------------------------------------
template <bool STORE_BF16>
__global__ __launch_bounds__(256) void gemm_mfma(
    const ushort* __restrict__ A, const ushort* __restrict__ W,
    const float* __restrict__ bias, void* __restrict__ C, int M)
{
    const int lane = threadIdx.x & 63;
    const int wave = threadIdx.x >> 6;
    const int ml   = lane & 15;
    const int quad = lane >> 4;
    const int m0   = blockIdx.x * 64 + wave * 16;

    int arow = m0 + ml; if (arow >= M) arow = M - 1;   // clamp loads
    const ushort* ap = A + arow * 128 + quad * 8;

    f32x4 acc[8];
#pragma unroll
    for (int ct = 0; ct < 8; ++ct) acc[ct] = (f32x4){0.f, 0.f, 0.f, 0.f};

#pragma unroll
    for (int ks = 0; ks < 128; ks += 32) {
        bf16x8 af = *reinterpret_cast<const bf16x8*>(ap + ks);
#pragma unroll
        for (int ct = 0; ct < 8; ++ct) {
            bf16x8 bf = *reinterpret_cast<const bf16x8*>(
                W + (ct * 16 + ml) * 128 + ks + quad * 8);
            acc[ct] = __builtin_amdgcn_mfma_f32_16x16x32_bf16(af, bf, acc[ct], 0, 0, 0);
        }
    }

#pragma unroll
    for (int ct = 0; ct < 8; ++ct) {
        int col = ct * 16 + ml;
        float bv = bias[col];
#pragma unroll
        for (int r = 0; r < 4; ++r) {
            int row = m0 + quad * 4 + r;
            if (row < M) {
                float v = acc[ct][r] + bv;
                if (STORE_BF16)
                    reinterpret_cast<ushort*>(C)[row * 128 + col] = cvt_bf16(v);
                else
                    reinterpret_cast<float*>(C)[row * 128 + col] = v;
            }
        }
    }
}

// ---------------------------------------------------------------------------
// CSR build: degree histogram, exclusive scan, scatter.
// ---------------------------------------------------------------------------
__global__ __launch_bounds__(256) void build_deg(
    const int* __restrict__ ei, int* __restrict__ deg)
{
    int e = blockIdx.x * 256 + threadIdx.x;
    if (e < N_EDGES) atomicAdd(&deg[ei[e]], 1);
}

__global__ __launch_bounds__(256) void scan_offsets(
    const int* __restrict__ deg, int* __restrict__ offsets,
    int* __restrict__ cursor)
{
    __shared__ int part[256];
    int t = threadIdx.x;
    int start = t * 98;
    int end = start + 98; if (end > N_NODES) end = N_NODES;
    if (start > N_NODES) start = N_NODES;
    int s = 0;
    for (int i = start; i < end; ++i) s += deg[i];
    part[t] = s;
    __syncthreads();
    for (int off = 1; off < 256; off <<= 1) {
        int v = (t >= off) ? part[t - off] : 0;
        __syncthreads();
        part[t] += v;
        __syncthreads();
    }
    int run = part[t] - s;
    for (int i = start; i < end; ++i) {
        offsets[i] = run;
        cursor[i] = run;
        run += deg[i];
    }
    if (t == 0) offsets[N_NODES] = N_EDGES;
}

__global__ __launch_bounds__(256) void scatter_edges(
    const int* __restrict__ ei, int* __restrict__ cursor,
    int* __restrict__ csr)
{
    int e = blockIdx.x * 256 + threadIdx.x;
    if (e >= N_EDGES) return;
    int pos = atomicAdd(&cursor[ei[e]], 1);
    csr[pos] = e;
}

// ---------------------------------------------------------------------------
// Fused attention, bf16 K/V/Q, one wave per node.
// Lane l holds dims {2l, 2l+1}; head h = l>>3 (8 lanes per head).
// 2-edge unroll for memory-level parallelism on the csr->ei->K/V chain.
// exp without max-subtraction (identical softmax; logits are O(+-10)).
// ---------------------------------------------------------------------------
__global__ __launch_bounds__(256) void fused_attn(
    const ushort* __restrict__ Q2, const ushort* __restrict__ K2,
    const ushort* __restrict__ V2, const int* __restrict__ ei,
    const float* __restrict__ attn_bias,
    const int* __restrict__ offsets, const int* __restrict__ csr,
    float* __restrict__ logits, ushort* __restrict__ AGG)
{
    const int lane = threadIdx.x & 63;
    const int wid  = threadIdx.x >> 6;
    const int n = blockIdx.x * 4 + wid;
    const int start = offsets[n], end = offsets[n + 1];
    const int h = lane >> 3;

    const uint* Ku = reinterpret_cast<const uint*>(K2);
    const uint* Vu = reinterpret_cast<const uint*>(V2);
    const int* srcs = ei + N_EDGES;

    uint qu = reinterpret_cast<const uint*>(Q2)[n * 64 + lane];
    float qx = bf16_lo(qu), qy = bf16_hi(qu);

    float z = 0.f, accx = 0.f, accy = 0.f;

    int i = start;
    for (; i + 1 < end; i += 2) {
        int e0 = csr[i], e1 = csr[i + 1];
        int s0 = srcs[e0], s1 = srcs[e1];
        uint ku0 = Ku[s0 * 64 + lane];
        uint ku1 = Ku[s1 * 64 + lane];
        uint vu0 = Vu[s0 * 64 + lane];
        uint vu1 = Vu[s1 * 64 + lane];
        float b0 = attn_bias[e0 * 8 + h];
        float b1 = attn_bias[e1 * 8 + h];

        float d0 = qx * bf16_lo(ku0) + qy * bf16_hi(ku0);
        float d1 = qx * bf16_lo(ku1) + qy * bf16_hi(ku1);
#pragma unroll
        for (int off = 1; off < 8; off <<= 1) {
            d0 += __shfl_xor(d0, off, 64);
            d1 += __shfl_xor(d1, off, 64);
        }
        float l0 = 0.25f * d0 + b0;
        float l1 = 0.25f * d1 + b1;
        if ((lane & 7) == 0) {
            logits[e0 * 8 + h] = l0;
            logits[e1 * 8 + h] = l1;
        }
        float p0 = __expf(l0);
        float p1 = __expf(l1);
        z += p0 + p1;
        accx += p0 * bf16_lo(vu0) + p1 * bf16_lo(vu1);
        accy += p0 * bf16_hi(vu0) + p1 * bf16_hi(vu1);
    }
    if (i < end) {
        int e0 = csr[i];
        int s0 = srcs[e0];
        uint ku0 = Ku[s0 * 64 + lane];
        uint vu0 = Vu[s0 * 64 + lane];
        float b0 = attn_bias[e0 * 8 + h];
        float d0 = qx * bf16_lo(ku0) + qy * bf16_hi(ku0);
#pragma unroll
        for (int off = 1; off < 8; off <<= 1) d0 += __shfl_xor(d0, off, 64);
        float l0 = 0.25f * d0 + b0;
        if ((lane & 7) == 0) logits[e0 * 8 + h] = l0;
        float p0 = __expf(l0);
        z += p0;
        accx += p0 * bf16_lo(vu0);
        accy += p0 * bf16_hi(vu0);
    }

    float inv = (z > 0.f) ? 1.f / z : 0.f;
    reinterpret_cast<uint*>(AGG)[n * 64 + lane] = pack2_bf16(accx * inv, accy * inv);
}

// ---------------------------------------------------------------------------
extern "C" void kernel_launch(void* const* d_in, const int* in_sizes, int n_in,
                              void* d_out, int out_size, void* d_ws, size_t ws_size,
                              hipStream_t stream)
{
    const float* x         = (const float*)d_in[0];
    const int*   ei        = (const int*)  d_in[1];
    const float* attn_bias = (const float*)d_in[2];
    const float* Wq = (const float*)d_in[3];
    const float* bq = (const float*)d_in[4];
    const float* Wk = (const float*)d_in[5];
    const float* bk = (const float*)d_in[6];
    const float* Wv = (const float*)d_in[7];
    const float* bv = (const float*)d_in[8];
    const float* Wo = (const float*)d_in[9];
    const float* bo = (const float*)d_in[10];

    float* out    = (float*)d_out;                // [N,128]
    float* logits = out + N_NODES * EMBED;        // [E,8] (output 1)

    ushort* xb   = (ushort*)d_ws;                 // N*128
    ushort* wb   = xb + NX;                       // 4*16384 (Wq,Wk,Wv,Wo)
    ushort* Qb   = wb + 4 * 16384;
    ushort* Kb   = Qb + NX;
    ushort* Vb   = Kb + NX;
    ushort* AGGb = Vb + NX;
    int* deg     = (int*)(AGGb + NX);
    int* offsets = deg + N_NODES;                 // N+1
    int* cursor  = offsets + N_NODES + 1;
    int* csr     = cursor + N_NODES;              // E

    hipMemsetAsync(deg, 0, N_NODES * sizeof(int), stream);

    int npairs = (NX + 4 * 16384) / 2;
    convert_all<<<(npairs + 255) / 256, 256, 0, stream>>>(x, Wq, Wk, Wv, Wo, xb, wb);

    int gblocks = (N_NODES + 63) / 64;
    gemm_mfma<true><<<gblocks, 256, 0, stream>>>(xb, wb,             bq, Qb, N_NODES);
    gemm_mfma<true><<<gblocks, 256, 0, stream>>>(xb, wb + 16384,     bk, Kb, N_NODES);
    gemm_mfma<true><<<gblocks, 256, 0, stream>>>(xb, wb + 2 * 16384, bv, Vb, N_NODES);

    build_deg<<<(N_EDGES + 255) / 256, 256, 0, stream>>>(ei, deg);
    scan_offsets<<<1, 256, 0, stream>>>(deg, offsets, cursor);
    scatter_edges<<<(N_EDGES + 255) / 256, 256, 0, stream>>>(ei, cursor, csr);

    fused_attn<<<N_NODES / 4, 256, 0, stream>>>(Qb, Kb, Vb, ei, attn_bias,
                                                offsets, csr, logits, AGGb);

    gemm_mfma<false><<<gblocks, 256, 0, stream>>>(AGGb, wb + 3 * 16384, bo, out, N_NODES);
}

// Round 4
// 270.922 us; speedup vs baseline: 1.4850x; 1.1587x over previous
//
#include <hip/hip_runtime.h>
#include <math.h>

#define N_NODES 25000
#define N_EDGES 400000
#define EMBED   128
#define HEADS   8
#define DK      16

typedef __attribute__((ext_vector_type(8))) short bf16x8;
typedef __attribute__((ext_vector_type(4))) float f32x4;
typedef unsigned int uint;
typedef unsigned short ushort;

__device__ inline uint pack2_bf16(float a, float b) {
    union { float f; uint u; } ua, ub;
    ua.f = a; ub.f = b;
    uint ra = (ua.u + 0x7FFFu + ((ua.u >> 16) & 1u)) >> 16;
    uint rb = (ub.u + 0x7FFFu + ((ub.u >> 16) & 1u)) >> 16;
    return (ra & 0xFFFFu) | (rb << 16);
}
__device__ inline ushort cvt_bf16(float a) {
    union { float f; uint u; } ua; ua.f = a;
    return (ushort)((ua.u + 0x7FFFu + ((ua.u >> 16) & 1u)) >> 16);
}
__device__ inline float bf16_lo(uint u) {
    union { uint u; float f; } x; x.u = u << 16; return x.f;
}
__device__ inline float bf16_hi(uint u) {
    union { uint u; float f; } x; x.u = u & 0xFFFF0000u; return x.f;
}

// ---------------------------------------------------------------------------
// Convert x (N*128) and the four 128x128 weights to bf16, pairwise.
// ---------------------------------------------------------------------------
#define NX (N_NODES * 128)
__global__ __launch_bounds__(256) void convert_all(
    const float* __restrict__ x,
    const float* __restrict__ Wq, const float* __restrict__ Wk,
    const float* __restrict__ Wv, const float* __restrict__ Wo,
    ushort* __restrict__ xb, ushort* __restrict__ wb)
{
    int i = blockIdx.x * 256 + threadIdx.x;   // pair index
    int base = i * 2;
    if (base < NX) {
        float2 v = *reinterpret_cast<const float2*>(x + base);
        reinterpret_cast<uint*>(xb)[i] = pack2_bf16(v.x, v.y);
    } else {
        int j = base - NX;
        if (j < 4 * 16384) {
            const float* src = (j < 16384) ? Wq + j
                             : (j < 32768) ? Wk + (j - 16384)
                             : (j < 49152) ? Wv + (j - 32768)
                             :               Wo + (j - 49152);
            float2 v = *reinterpret_cast<const float2*>(src);
            reinterpret_cast<uint*>(wb)[j >> 1] = pack2_bf16(v.x, v.y);
        }
    }
}

// ---------------------------------------------------------------------------
// MFMA GEMM: C[m][n] = sum_k A[m][k] * W[n][k] + bias[n]
// Fused Q/K/V variant: blockIdx.y in {0,1,2} selects weights/bias/dst.
// ---------------------------------------------------------------------------
__global__ __launch_bounds__(256) void gemm_qkv(
    const ushort* __restrict__ A, const ushort* __restrict__ Wall,
    const float* __restrict__ bq, const float* __restrict__ bk,
    const float* __restrict__ bv,
    ushort* __restrict__ Qb, ushort* __restrict__ Kb, ushort* __restrict__ Vb,
    int M)
{
    const int which = blockIdx.y;
    const ushort* W = Wall + which * 16384;
    const float* bias = (which == 0) ? bq : (which == 1) ? bk : bv;
    ushort* C = (which == 0) ? Qb : (which == 1) ? Kb : Vb;

    const int lane = threadIdx.x & 63;
    const int wave = threadIdx.x >> 6;
    const int ml   = lane & 15;
    const int quad = lane >> 4;
    const int m0   = blockIdx.x * 64 + wave * 16;

    int arow = m0 + ml; if (arow >= M) arow = M - 1;
    const ushort* ap = A + arow * 128 + quad * 8;

    f32x4 acc[8];
#pragma unroll
    for (int ct = 0; ct < 8; ++ct) acc[ct] = (f32x4){0.f, 0.f, 0.f, 0.f};

#pragma unroll
    for (int ks = 0; ks < 128; ks += 32) {
        bf16x8 af = *reinterpret_cast<const bf16x8*>(ap + ks);
#pragma unroll
        for (int ct = 0; ct < 8; ++ct) {
            bf16x8 bf = *reinterpret_cast<const bf16x8*>(
                W + (ct * 16 + ml) * 128 + ks + quad * 8);
            acc[ct] = __builtin_amdgcn_mfma_f32_16x16x32_bf16(af, bf, acc[ct], 0, 0, 0);
        }
    }

#pragma unroll
    for (int ct = 0; ct < 8; ++ct) {
        int col = ct * 16 + ml;
        float bv_ = bias[col];
#pragma unroll
        for (int r = 0; r < 4; ++r) {
            int row = m0 + quad * 4 + r;
            if (row < M)
                C[row * 128 + col] = cvt_bf16(acc[ct][r] + bv_);
        }
    }
}

// Final projection: A bf16 [M,128] @ W^T + bias -> fp32 out
__global__ __launch_bounds__(256) void gemm_out(
    const ushort* __restrict__ A, const ushort* __restrict__ W,
    const float* __restrict__ bias, float* __restrict__ C, int M)
{
    const int lane = threadIdx.x & 63;
    const int wave = threadIdx.x >> 6;
    const int ml   = lane & 15;
    const int quad = lane >> 4;
    const int m0   = blockIdx.x * 64 + wave * 16;

    int arow = m0 + ml; if (arow >= M) arow = M - 1;
    const ushort* ap = A + arow * 128 + quad * 8;

    f32x4 acc[8];
#pragma unroll
    for (int ct = 0; ct < 8; ++ct) acc[ct] = (f32x4){0.f, 0.f, 0.f, 0.f};

#pragma unroll
    for (int ks = 0; ks < 128; ks += 32) {
        bf16x8 af = *reinterpret_cast<const bf16x8*>(ap + ks);
#pragma unroll
        for (int ct = 0; ct < 8; ++ct) {
            bf16x8 bf = *reinterpret_cast<const bf16x8*>(
                W + (ct * 16 + ml) * 128 + ks + quad * 8);
            acc[ct] = __builtin_amdgcn_mfma_f32_16x16x32_bf16(af, bf, acc[ct], 0, 0, 0);
        }
    }

#pragma unroll
    for (int ct = 0; ct < 8; ++ct) {
        int col = ct * 16 + ml;
        float bv_ = bias[col];
#pragma unroll
        for (int r = 0; r < 4; ++r) {
            int row = m0 + quad * 4 + r;
            if (row < M)
                C[row * 128 + col] = acc[ct][r] + bv_;
        }
    }
}

// ---------------------------------------------------------------------------
// CSR build: degree histogram, exclusive scan (1024-wide), scatter.
// ---------------------------------------------------------------------------
__global__ __launch_bounds__(256) void build_deg(
    const int* __restrict__ ei, int* __restrict__ deg)
{
    int t = blockIdx.x * 256 + threadIdx.x;
    int e = t * 2;
    if (e + 1 < N_EDGES) {
        int2 d = *reinterpret_cast<const int2*>(ei + e);
        atomicAdd(&deg[d.x], 1);
        atomicAdd(&deg[d.y], 1);
    } else if (e < N_EDGES) {
        atomicAdd(&deg[ei[e]], 1);
    }
}

#define SCAN_T 1024
__global__ __launch_bounds__(SCAN_T) void scan_offsets(
    const int* __restrict__ deg, int* __restrict__ offsets,
    int* __restrict__ cursor)
{
    __shared__ int part[SCAN_T];
    int t = threadIdx.x;
    const int chunk = (N_NODES + SCAN_T - 1) / SCAN_T;   // 25
    int start = t * chunk;
    int end = start + chunk; if (end > N_NODES) end = N_NODES;
    if (start > N_NODES) start = N_NODES;
    int s = 0;
    for (int i = start; i < end; ++i) s += deg[i];
    part[t] = s;
    __syncthreads();
    for (int off = 1; off < SCAN_T; off <<= 1) {
        int v = (t >= off) ? part[t - off] : 0;
        __syncthreads();
        part[t] += v;
        __syncthreads();
    }
    int run = part[t] - s;
    for (int i = start; i < end; ++i) {
        offsets[i] = run;
        cursor[i] = run;
        run += deg[i];
    }
    if (t == 0) offsets[N_NODES] = N_EDGES;
}

__global__ __launch_bounds__(256) void scatter_edges(
    const int* __restrict__ ei, int* __restrict__ cursor,
    int* __restrict__ csr)
{
    int e = blockIdx.x * 256 + threadIdx.x;
    if (e >= N_EDGES) return;
    int pos = atomicAdd(&cursor[ei[e]], 1);
    csr[pos] = e;
}

// ---------------------------------------------------------------------------
// Fused attention v3. One wave per node; lane l holds dims {2l,2l+1};
// head h = l>>3. Edge ids + srcs preloaded per-lane (csr is contiguous per
// node) and broadcast via __shfl -> inner loop has only INDEPENDENT
// K/V/bias loads, 4 edges in flight.
// ---------------------------------------------------------------------------
__global__ __launch_bounds__(256) void fused_attn(
    const ushort* __restrict__ Q2, const ushort* __restrict__ K2,
    const ushort* __restrict__ V2, const int* __restrict__ ei,
    const float* __restrict__ attn_bias,
    const int* __restrict__ offsets, const int* __restrict__ csr,
    float* __restrict__ logits, ushort* __restrict__ AGG)
{
    const int lane = threadIdx.x & 63;
    const int wid  = threadIdx.x >> 6;
    const int n = blockIdx.x * 4 + wid;
    const int start = offsets[n], end = offsets[n + 1];
    const int h = lane >> 3;

    const uint* Ku = reinterpret_cast<const uint*>(K2);
    const uint* Vu = reinterpret_cast<const uint*>(V2);
    const int* srcs = ei + N_EDGES;

    uint qu = reinterpret_cast<const uint*>(Q2)[n * 64 + lane];
    float qx = bf16_lo(qu), qy = bf16_hi(qu);

    float z = 0.f, accx = 0.f, accy = 0.f;

    for (int base = start; base < end; base += 64) {
        int cnt = end - base; if (cnt > 64) cnt = 64;
        int e_l = 0, s_l = 0;
        if (lane < cnt) {
            e_l = csr[base + lane];
            s_l = srcs[e_l];
        }
        int j = 0;
        for (; j + 3 < cnt; j += 4) {
            int e0 = __shfl(e_l, j, 64),     e1 = __shfl(e_l, j + 1, 64);
            int e2 = __shfl(e_l, j + 2, 64), e3 = __shfl(e_l, j + 3, 64);
            int s0 = __shfl(s_l, j, 64),     s1 = __shfl(s_l, j + 1, 64);
            int s2 = __shfl(s_l, j + 2, 64), s3 = __shfl(s_l, j + 3, 64);
            uint ku0 = Ku[s0 * 64 + lane], ku1 = Ku[s1 * 64 + lane];
            uint ku2 = Ku[s2 * 64 + lane], ku3 = Ku[s3 * 64 + lane];
            uint vu0 = Vu[s0 * 64 + lane], vu1 = Vu[s1 * 64 + lane];
            uint vu2 = Vu[s2 * 64 + lane], vu3 = Vu[s3 * 64 + lane];
            float b0 = attn_bias[e0 * 8 + h], b1 = attn_bias[e1 * 8 + h];
            float b2 = attn_bias[e2 * 8 + h], b3 = attn_bias[e3 * 8 + h];

            float d0 = qx * bf16_lo(ku0) + qy * bf16_hi(ku0);
            float d1 = qx * bf16_lo(ku1) + qy * bf16_hi(ku1);
            float d2 = qx * bf16_lo(ku2) + qy * bf16_hi(ku2);
            float d3 = qx * bf16_lo(ku3) + qy * bf16_hi(ku3);
#pragma unroll
            for (int off = 1; off < 8; off <<= 1) {
                d0 += __shfl_xor(d0, off, 64);
                d1 += __shfl_xor(d1, off, 64);
                d2 += __shfl_xor(d2, off, 64);
                d3 += __shfl_xor(d3, off, 64);
            }
            float l0 = 0.25f * d0 + b0, l1 = 0.25f * d1 + b1;
            float l2 = 0.25f * d2 + b2, l3 = 0.25f * d3 + b3;
            if ((lane & 7) == 0) {
                logits[e0 * 8 + h] = l0;
                logits[e1 * 8 + h] = l1;
                logits[e2 * 8 + h] = l2;
                logits[e3 * 8 + h] = l3;
            }
            float p0 = __expf(l0), p1 = __expf(l1);
            float p2 = __expf(l2), p3 = __expf(l3);
            z += (p0 + p1) + (p2 + p3);
            accx += p0 * bf16_lo(vu0) + p1 * bf16_lo(vu1)
                  + p2 * bf16_lo(vu2) + p3 * bf16_lo(vu3);
            accy += p0 * bf16_hi(vu0) + p1 * bf16_hi(vu1)
                  + p2 * bf16_hi(vu2) + p3 * bf16_hi(vu3);
        }
        for (; j < cnt; ++j) {
            int e0 = __shfl(e_l, j, 64);
            int s0 = __shfl(s_l, j, 64);
            uint ku0 = Ku[s0 * 64 + lane];
            uint vu0 = Vu[s0 * 64 + lane];
            float b0 = attn_bias[e0 * 8 + h];
            float d0 = qx * bf16_lo(ku0) + qy * bf16_hi(ku0);
#pragma unroll
            for (int off = 1; off < 8; off <<= 1) d0 += __shfl_xor(d0, off, 64);
            float l0 = 0.25f * d0 + b0;
            if ((lane & 7) == 0) logits[e0 * 8 + h] = l0;
            float p0 = __expf(l0);
            z += p0;
            accx += p0 * bf16_lo(vu0);
            accy += p0 * bf16_hi(vu0);
        }
    }

    float inv = (z > 0.f) ? 1.f / z : 0.f;
    reinterpret_cast<uint*>(AGG)[n * 64 + lane] = pack2_bf16(accx * inv, accy * inv);
}

// ---------------------------------------------------------------------------
extern "C" void kernel_launch(void* const* d_in, const int* in_sizes, int n_in,
                              void* d_out, int out_size, void* d_ws, size_t ws_size,
                              hipStream_t stream)
{
    const float* x         = (const float*)d_in[0];
    const int*   ei        = (const int*)  d_in[1];
    const float* attn_bias = (const float*)d_in[2];
    const float* Wq = (const float*)d_in[3];
    const float* bq = (const float*)d_in[4];
    const float* Wk = (const float*)d_in[5];
    const float* bk = (const float*)d_in[6];
    const float* Wv = (const float*)d_in[7];
    const float* bv = (const float*)d_in[8];
    const float* Wo = (const float*)d_in[9];
    const float* bo = (const float*)d_in[10];

    float* out    = (float*)d_out;                // [N,128]
    float* logits = out + N_NODES * EMBED;        // [E,8] (output 1)

    ushort* xb   = (ushort*)d_ws;                 // N*128
    ushort* wb   = xb + NX;                       // 4*16384 (Wq,Wk,Wv,Wo)
    ushort* Qb   = wb + 4 * 16384;
    ushort* Kb   = Qb + NX;
    ushort* Vb   = Kb + NX;
    ushort* AGGb = Vb + NX;
    int* deg     = (int*)(AGGb + NX);
    int* offsets = deg + N_NODES;                 // N+1
    int* cursor  = offsets + N_NODES + 1;
    int* csr     = cursor + N_NODES;              // E

    hipMemsetAsync(deg, 0, N_NODES * sizeof(int), stream);

    int npairs = (NX + 4 * 16384) / 2;
    convert_all<<<(npairs + 255) / 256, 256, 0, stream>>>(x, Wq, Wk, Wv, Wo, xb, wb);

    int gblocks = (N_NODES + 63) / 64;
    dim3 qkvgrid(gblocks, 3);
    gemm_qkv<<<qkvgrid, 256, 0, stream>>>(xb, wb, bq, bk, bv, Qb, Kb, Vb, N_NODES);

    build_deg<<<(N_EDGES / 2 + 255) / 256, 256, 0, stream>>>(ei, deg);
    scan_offsets<<<1, SCAN_T, 0, stream>>>(deg, offsets, cursor);
    scatter_edges<<<(N_EDGES + 255) / 256, 256, 0, stream>>>(ei, cursor, csr);

    fused_attn<<<N_NODES / 4, 256, 0, stream>>>(Qb, Kb, Vb, ei, attn_bias,
                                                offsets, csr, logits, AGGb);

    gemm_out<<<gblocks, 256, 0, stream>>>(AGGb, wb + 3 * 16384, bo, out, N_NODES);
}

// Round 5
// 241.175 us; speedup vs baseline: 1.6681x; 1.1233x over previous
//
#include <hip/hip_runtime.h>
#include <math.h>

#define N_NODES 25000
#define N_EDGES 400000
#define EMBED   128
#define HEADS   8
#define DK      16
#define NBLK    98        // ceil(25000/256)

typedef __attribute__((ext_vector_type(8))) short bf16x8;
typedef __attribute__((ext_vector_type(4))) float f32x4;
typedef unsigned int uint;
typedef unsigned short ushort;

__device__ inline uint pack2_bf16(float a, float b) {
    union { float f; uint u; } ua, ub;
    ua.f = a; ub.f = b;
    uint ra = (ua.u + 0x7FFFu + ((ua.u >> 16) & 1u)) >> 16;
    uint rb = (ub.u + 0x7FFFu + ((ub.u >> 16) & 1u)) >> 16;
    return (ra & 0xFFFFu) | (rb << 16);
}
__device__ inline ushort cvt_bf16(float a) {
    union { float f; uint u; } ua; ua.f = a;
    return (ushort)((ua.u + 0x7FFFu + ((ua.u >> 16) & 1u)) >> 16);
}
__device__ inline float bf16_lo(uint u) {
    union { uint u; float f; } x; x.u = u << 16; return x.f;
}
__device__ inline float bf16_hi(uint u) {
    union { uint u; float f; } x; x.u = u & 0xFFFF0000u; return x.f;
}

// ---------------------------------------------------------------------------
// Convert x (N*128) and the four 128x128 weights to bf16; zero deg inline.
// ---------------------------------------------------------------------------
#define NX (N_NODES * 128)
__global__ __launch_bounds__(256) void convert_all(
    const float* __restrict__ x,
    const float* __restrict__ Wq, const float* __restrict__ Wk,
    const float* __restrict__ Wv, const float* __restrict__ Wo,
    ushort* __restrict__ xb, ushort* __restrict__ wb, int* __restrict__ deg)
{
    int i = blockIdx.x * 256 + threadIdx.x;   // pair index
    if (i < N_NODES) deg[i] = 0;
    int base = i * 2;
    if (base < NX) {
        float2 v = *reinterpret_cast<const float2*>(x + base);
        reinterpret_cast<uint*>(xb)[i] = pack2_bf16(v.x, v.y);
    } else {
        int j = base - NX;
        if (j < 4 * 16384) {
            const float* src = (j < 16384) ? Wq + j
                             : (j < 32768) ? Wk + (j - 16384)
                             : (j < 49152) ? Wv + (j - 32768)
                             :               Wo + (j - 49152);
            float2 v = *reinterpret_cast<const float2*>(src);
            reinterpret_cast<uint*>(wb)[j >> 1] = pack2_bf16(v.x, v.y);
        }
    }
}

// ---------------------------------------------------------------------------
// MFMA GEMM for Q/K/V: blockIdx.y in {0,1,2} selects weights/bias/dst.
// Q goes to Qb [row*128+col] (bf16). K/V go interleaved into KVu:
// ushort index = row*256 + (col>>1)*4 + (col&1) + (V ? 2 : 0)
// so fused_attn lane l reads uint2 {Kpair(2l,2l+1), Vpair(2l,2l+1)}.
// ---------------------------------------------------------------------------
__global__ __launch_bounds__(256) void gemm_qkv(
    const ushort* __restrict__ A, const ushort* __restrict__ Wall,
    const float* __restrict__ bq, const float* __restrict__ bk,
    const float* __restrict__ bv,
    ushort* __restrict__ Qb, ushort* __restrict__ KVu,
    int M)
{
    const int which = blockIdx.y;
    const ushort* W = Wall + which * 16384;
    const float* bias = (which == 0) ? bq : (which == 1) ? bk : bv;

    const int lane = threadIdx.x & 63;
    const int wave = threadIdx.x >> 6;
    const int ml   = lane & 15;
    const int quad = lane >> 4;
    const int m0   = blockIdx.x * 64 + wave * 16;

    int arow = m0 + ml; if (arow >= M) arow = M - 1;
    const ushort* ap = A + arow * 128 + quad * 8;

    f32x4 acc[8];
#pragma unroll
    for (int ct = 0; ct < 8; ++ct) acc[ct] = (f32x4){0.f, 0.f, 0.f, 0.f};

#pragma unroll
    for (int ks = 0; ks < 128; ks += 32) {
        bf16x8 af = *reinterpret_cast<const bf16x8*>(ap + ks);
#pragma unroll
        for (int ct = 0; ct < 8; ++ct) {
            bf16x8 bf = *reinterpret_cast<const bf16x8*>(
                W + (ct * 16 + ml) * 128 + ks + quad * 8);
            acc[ct] = __builtin_amdgcn_mfma_f32_16x16x32_bf16(af, bf, acc[ct], 0, 0, 0);
        }
    }

#pragma unroll
    for (int ct = 0; ct < 8; ++ct) {
        int col = ct * 16 + ml;
        float bv_ = bias[col];
#pragma unroll
        for (int r = 0; r < 4; ++r) {
            int row = m0 + quad * 4 + r;
            if (row >= M) continue;
            ushort v = cvt_bf16(acc[ct][r] + bv_);
            if (which == 0) {
                Qb[row * 128 + col] = v;
            } else {
                KVu[row * 256 + (col >> 1) * 4 + (col & 1) + ((which == 2) ? 2 : 0)] = v;
            }
        }
    }
}

// Final projection: A bf16 [M,128] @ W^T + bias -> fp32 out
__global__ __launch_bounds__(256) void gemm_out(
    const ushort* __restrict__ A, const ushort* __restrict__ W,
    const float* __restrict__ bias, float* __restrict__ C, int M)
{
    const int lane = threadIdx.x & 63;
    const int wave = threadIdx.x >> 6;
    const int ml   = lane & 15;
    const int quad = lane >> 4;
    const int m0   = blockIdx.x * 64 + wave * 16;

    int arow = m0 + ml; if (arow >= M) arow = M - 1;
    const ushort* ap = A + arow * 128 + quad * 8;

    f32x4 acc[8];
#pragma unroll
    for (int ct = 0; ct < 8; ++ct) acc[ct] = (f32x4){0.f, 0.f, 0.f, 0.f};

#pragma unroll
    for (int ks = 0; ks < 128; ks += 32) {
        bf16x8 af = *reinterpret_cast<const bf16x8*>(ap + ks);
#pragma unroll
        for (int ct = 0; ct < 8; ++ct) {
            bf16x8 bf = *reinterpret_cast<const bf16x8*>(
                W + (ct * 16 + ml) * 128 + ks + quad * 8);
            acc[ct] = __builtin_amdgcn_mfma_f32_16x16x32_bf16(af, bf, acc[ct], 0, 0, 0);
        }
    }

#pragma unroll
    for (int ct = 0; ct < 8; ++ct) {
        int col = ct * 16 + ml;
        float bv_ = bias[col];
#pragma unroll
        for (int r = 0; r < 4; ++r) {
            int row = m0 + quad * 4 + r;
            if (row < M)
                C[row * 128 + col] = acc[ct][r] + bv_;
        }
    }
}

// ---------------------------------------------------------------------------
// CSR build: histogram + hierarchical scan (3 small kernels) + scatter.
// ---------------------------------------------------------------------------
__global__ __launch_bounds__(256) void build_deg(
    const int* __restrict__ ei, int* __restrict__ deg)
{
    int t = blockIdx.x * 256 + threadIdx.x;
    int e = t * 2;
    if (e + 1 < N_EDGES) {
        int2 d = *reinterpret_cast<const int2*>(ei + e);
        atomicAdd(&deg[d.x], 1);
        atomicAdd(&deg[d.y], 1);
    } else if (e < N_EDGES) {
        atomicAdd(&deg[ei[e]], 1);
    }
}

// per-block inclusive scan -> exclusive prefix (local) + block sums
__global__ __launch_bounds__(256) void scan_blocks(
    const int* __restrict__ deg, int* __restrict__ excl, int* __restrict__ bsum)
{
    __shared__ int sh[256];
    int t = threadIdx.x;
    int gid = blockIdx.x * 256 + t;
    int v = (gid < N_NODES) ? deg[gid] : 0;
    sh[t] = v;
    __syncthreads();
#pragma unroll
    for (int off = 1; off < 256; off <<= 1) {
        int u = (t >= off) ? sh[t - off] : 0;
        __syncthreads();
        sh[t] += u;
        __syncthreads();
    }
    if (gid < N_NODES) excl[gid] = sh[t] - v;   // local exclusive prefix
    if (t == 255) bsum[blockIdx.x] = sh[255];
}

// scan the 98 block sums (one small block)
__global__ __launch_bounds__(128) void scan_tops(
    const int* __restrict__ bsum, int* __restrict__ bbase)
{
    __shared__ int sh[128];
    int t = threadIdx.x;
    int v = (t < NBLK) ? bsum[t] : 0;
    sh[t] = v;
    __syncthreads();
#pragma unroll
    for (int off = 1; off < 128; off <<= 1) {
        int u = (t >= off) ? sh[t - off] : 0;
        __syncthreads();
        sh[t] += u;
        __syncthreads();
    }
    if (t < NBLK) bbase[t] = sh[t] - v;
}

// apply block bases; produce offsets + cursor
__global__ __launch_bounds__(256) void scan_apply(
    int* __restrict__ excl, const int* __restrict__ bbase,
    int* __restrict__ cursor)
{
    int t = threadIdx.x;
    int gid = blockIdx.x * 256 + t;
    if (gid < N_NODES) {
        int o = excl[gid] + bbase[blockIdx.x];
        excl[gid] = o;         // excl buffer IS offsets
        cursor[gid] = o;
    }
    if (blockIdx.x == 0 && t == 0) excl[N_NODES] = N_EDGES;
}

__global__ __launch_bounds__(256) void scatter_edges(
    const int* __restrict__ ei, int* __restrict__ cursor,
    int* __restrict__ csr)
{
    int e = blockIdx.x * 256 + threadIdx.x;
    if (e >= N_EDGES) return;
    int pos = atomicAdd(&cursor[ei[e]], 1);
    csr[pos] = e;
}

// ---------------------------------------------------------------------------
// Fused attention v4. One wave per node; lane l holds dims {2l,2l+1};
// head h = l>>3. Edge ids + srcs preloaded per-lane and broadcast via __shfl.
// KV interleaved: one uint2 load per edge = {K pair, V pair}. 8-edge unroll.
// ---------------------------------------------------------------------------
__global__ __launch_bounds__(256) void fused_attn(
    const ushort* __restrict__ Q2, const uint2* __restrict__ KV,
    const int* __restrict__ ei, const float* __restrict__ attn_bias,
    const int* __restrict__ offsets, const int* __restrict__ csr,
    float* __restrict__ logits, ushort* __restrict__ AGG)
{
    const int lane = threadIdx.x & 63;
    const int wid  = threadIdx.x >> 6;
    const int n = blockIdx.x * 4 + wid;
    const int start = offsets[n], end = offsets[n + 1];
    const int h = lane >> 3;

    const int* srcs = ei + N_EDGES;

    uint qu = reinterpret_cast<const uint*>(Q2)[n * 64 + lane];
    float qx = bf16_lo(qu), qy = bf16_hi(qu);

    float z = 0.f, accx = 0.f, accy = 0.f;

    for (int base = start; base < end; base += 64) {
        int cnt = end - base; if (cnt > 64) cnt = 64;
        int e_l = 0, s_l = 0;
        if (lane < cnt) {
            e_l = csr[base + lane];
            s_l = srcs[e_l];
        }
        int j = 0;
        for (; j + 7 < cnt; j += 8) {
            int ee[8], ss[8];
#pragma unroll
            for (int u = 0; u < 8; ++u) {
                ee[u] = __shfl(e_l, j + u, 64);
                ss[u] = __shfl(s_l, j + u, 64);
            }
            uint2 kv[8];
#pragma unroll
            for (int u = 0; u < 8; ++u) kv[u] = KV[ss[u] * 64 + lane];
            float bb[8];
#pragma unroll
            for (int u = 0; u < 8; ++u) bb[u] = attn_bias[ee[u] * 8 + h];
            float d[8];
#pragma unroll
            for (int u = 0; u < 8; ++u)
                d[u] = qx * bf16_lo(kv[u].x) + qy * bf16_hi(kv[u].x);
#pragma unroll
            for (int off = 1; off < 8; off <<= 1) {
#pragma unroll
                for (int u = 0; u < 8; ++u)
                    d[u] += __shfl_xor(d[u], off, 64);
            }
#pragma unroll
            for (int u = 0; u < 8; ++u) {
                float l = 0.25f * d[u] + bb[u];
                if ((lane & 7) == 0) logits[ee[u] * 8 + h] = l;
                float p = __expf(l);
                z += p;
                accx += p * bf16_lo(kv[u].y);
                accy += p * bf16_hi(kv[u].y);
            }
        }
        for (; j < cnt; ++j) {
            int e0 = __shfl(e_l, j, 64);
            int s0 = __shfl(s_l, j, 64);
            uint2 kv0 = KV[s0 * 64 + lane];
            float b0 = attn_bias[e0 * 8 + h];
            float d0 = qx * bf16_lo(kv0.x) + qy * bf16_hi(kv0.x);
#pragma unroll
            for (int off = 1; off < 8; off <<= 1) d0 += __shfl_xor(d0, off, 64);
            float l0 = 0.25f * d0 + b0;
            if ((lane & 7) == 0) logits[e0 * 8 + h] = l0;
            float p0 = __expf(l0);
            z += p0;
            accx += p0 * bf16_lo(kv0.y);
            accy += p0 * bf16_hi(kv0.y);
        }
    }

    float inv = (z > 0.f) ? 1.f / z : 0.f;
    reinterpret_cast<uint*>(AGG)[n * 64 + lane] = pack2_bf16(accx * inv, accy * inv);
}

// ---------------------------------------------------------------------------
extern "C" void kernel_launch(void* const* d_in, const int* in_sizes, int n_in,
                              void* d_out, int out_size, void* d_ws, size_t ws_size,
                              hipStream_t stream)
{
    const float* x         = (const float*)d_in[0];
    const int*   ei        = (const int*)  d_in[1];
    const float* attn_bias = (const float*)d_in[2];
    const float* Wq = (const float*)d_in[3];
    const float* bq = (const float*)d_in[4];
    const float* Wk = (const float*)d_in[5];
    const float* bk = (const float*)d_in[6];
    const float* Wv = (const float*)d_in[7];
    const float* bv = (const float*)d_in[8];
    const float* Wo = (const float*)d_in[9];
    const float* bo = (const float*)d_in[10];

    float* out    = (float*)d_out;                // [N,128]
    float* logits = out + N_NODES * EMBED;        // [E,8] (output 1)

    ushort* xb   = (ushort*)d_ws;                 // N*128
    ushort* wb   = xb + NX;                       // 4*16384 (Wq,Wk,Wv,Wo)
    ushort* Qb   = wb + 4 * 16384;                // N*128
    ushort* KVu  = Qb + NX;                       // N*256 (K/V interleaved)
    ushort* AGGb = KVu + 2 * NX;                  // N*128
    int* deg     = (int*)(AGGb + NX);
    int* offsets = deg + N_NODES;                 // N+1 (also excl buffer)
    int* cursor  = offsets + N_NODES + 1;
    int* csr     = cursor + N_NODES;              // E
    int* bsum    = csr + N_EDGES;                 // NBLK
    int* bbase   = bsum + NBLK;                   // NBLK

    int npairs = (NX + 4 * 16384) / 2;
    convert_all<<<(npairs + 255) / 256, 256, 0, stream>>>(x, Wq, Wk, Wv, Wo, xb, wb, deg);

    int gblocks = (N_NODES + 63) / 64;
    dim3 qkvgrid(gblocks, 3);
    gemm_qkv<<<qkvgrid, 256, 0, stream>>>(xb, wb, bq, bk, bv, Qb, KVu, N_NODES);

    build_deg<<<(N_EDGES / 2 + 255) / 256, 256, 0, stream>>>(ei, deg);
    scan_blocks<<<NBLK, 256, 0, stream>>>(deg, offsets, bsum);
    scan_tops<<<1, 128, 0, stream>>>(bsum, bbase);
    scan_apply<<<NBLK, 256, 0, stream>>>(offsets, bbase, cursor);
    scatter_edges<<<(N_EDGES + 255) / 256, 256, 0, stream>>>(ei, cursor, csr);

    fused_attn<<<N_NODES / 4, 256, 0, stream>>>(Qb, (const uint2*)KVu, ei, attn_bias,
                                                offsets, csr, logits, AGGb);

    gemm_out<<<gblocks, 256, 0, stream>>>(AGGb, wb + 3 * 16384, bo, out, N_NODES);
}

// Round 6
// 213.977 us; speedup vs baseline: 1.8802x; 1.1271x over previous
//
#include <hip/hip_runtime.h>
#include <math.h>

#define N_NODES 25000
#define N_EDGES 400000
#define EMBED   128
#define HEADS   8
#define DK      16
#define NBLK    98        // ceil(25000/256)

typedef __attribute__((ext_vector_type(8))) short bf16x8;
typedef __attribute__((ext_vector_type(4))) float f32x4;
typedef unsigned int uint;
typedef unsigned short ushort;

__device__ inline uint pack2_bf16(float a, float b) {
    union { float f; uint u; } ua, ub;
    ua.f = a; ub.f = b;
    uint ra = (ua.u + 0x7FFFu + ((ua.u >> 16) & 1u)) >> 16;
    uint rb = (ub.u + 0x7FFFu + ((ub.u >> 16) & 1u)) >> 16;
    return (ra & 0xFFFFu) | (rb << 16);
}
__device__ inline ushort cvt_bf16(float a) {
    union { float f; uint u; } ua; ua.f = a;
    return (ushort)((ua.u + 0x7FFFu + ((ua.u >> 16) & 1u)) >> 16);
}
__device__ inline float bf16_lo(uint u) {
    union { uint u; float f; } x; x.u = u << 16; return x.f;
}
__device__ inline float bf16_hi(uint u) {
    union { uint u; float f; } x; x.u = u & 0xFFFF0000u; return x.f;
}

// ---------------------------------------------------------------------------
// Convert x (N*128) and the four 128x128 weights to bf16; zero deg inline.
// ---------------------------------------------------------------------------
#define NX (N_NODES * 128)
__global__ __launch_bounds__(256) void convert_all(
    const float* __restrict__ x,
    const float* __restrict__ Wq, const float* __restrict__ Wk,
    const float* __restrict__ Wv, const float* __restrict__ Wo,
    ushort* __restrict__ xb, ushort* __restrict__ wb, int* __restrict__ deg)
{
    int i = blockIdx.x * 256 + threadIdx.x;   // pair index
    if (i < N_NODES) deg[i] = 0;
    int base = i * 2;
    if (base < NX) {
        float2 v = *reinterpret_cast<const float2*>(x + base);
        reinterpret_cast<uint*>(xb)[i] = pack2_bf16(v.x, v.y);
    } else {
        int j = base - NX;
        if (j < 4 * 16384) {
            const float* src = (j < 16384) ? Wq + j
                             : (j < 32768) ? Wk + (j - 16384)
                             : (j < 49152) ? Wv + (j - 32768)
                             :               Wo + (j - 49152);
            float2 v = *reinterpret_cast<const float2*>(src);
            reinterpret_cast<uint*>(wb)[j >> 1] = pack2_bf16(v.x, v.y);
        }
    }
}

// ---------------------------------------------------------------------------
// MFMA GEMM for Q/K/V + degree histogram.
// blockIdx.y in {0,1,2}: GEMM with weights/bias q/k/v.
// blockIdx.y == 3: degree histogram over ei[0..E) (independent work).
// Q -> Qb [row*128+col] bf16. K/V interleaved in KVu:
//   ushort idx = row*256 + (col>>1)*4 + (col&1) + (V ? 2 : 0)
// so fused_attn lane l loads uint2 {Kpair(2l,2l+1), Vpair(2l,2l+1)}.
// ---------------------------------------------------------------------------
__global__ __launch_bounds__(256) void gemm_qkv_deg(
    const ushort* __restrict__ A, const ushort* __restrict__ Wall,
    const float* __restrict__ bq, const float* __restrict__ bk,
    const float* __restrict__ bv,
    ushort* __restrict__ Qb, ushort* __restrict__ KVu,
    const int* __restrict__ ei, int* __restrict__ deg,
    int M)
{
    const int which = blockIdx.y;
    if (which == 3) {
        int t = blockIdx.x * 256 + threadIdx.x;
        int e = t * 4;
        if (e + 3 < N_EDGES) {
            int4 d = *reinterpret_cast<const int4*>(ei + e);
            atomicAdd(&deg[d.x], 1);
            atomicAdd(&deg[d.y], 1);
            atomicAdd(&deg[d.z], 1);
            atomicAdd(&deg[d.w], 1);
        } else {
            for (; e < N_EDGES && e < t * 4 + 4; ++e)
                atomicAdd(&deg[ei[e]], 1);
        }
        return;
    }

    const ushort* W = Wall + which * 16384;
    const float* bias = (which == 0) ? bq : (which == 1) ? bk : bv;

    const int lane = threadIdx.x & 63;
    const int wave = threadIdx.x >> 6;
    const int ml   = lane & 15;
    const int quad = lane >> 4;
    const int m0   = blockIdx.x * 64 + wave * 16;

    int arow = m0 + ml; if (arow >= M) arow = M - 1;
    const ushort* ap = A + arow * 128 + quad * 8;

    f32x4 acc[8];
#pragma unroll
    for (int ct = 0; ct < 8; ++ct) acc[ct] = (f32x4){0.f, 0.f, 0.f, 0.f};

#pragma unroll
    for (int ks = 0; ks < 128; ks += 32) {
        bf16x8 af = *reinterpret_cast<const bf16x8*>(ap + ks);
#pragma unroll
        for (int ct = 0; ct < 8; ++ct) {
            bf16x8 bf = *reinterpret_cast<const bf16x8*>(
                W + (ct * 16 + ml) * 128 + ks + quad * 8);
            acc[ct] = __builtin_amdgcn_mfma_f32_16x16x32_bf16(af, bf, acc[ct], 0, 0, 0);
        }
    }

#pragma unroll
    for (int ct = 0; ct < 8; ++ct) {
        int col = ct * 16 + ml;
        float bv_ = bias[col];
#pragma unroll
        for (int r = 0; r < 4; ++r) {
            int row = m0 + quad * 4 + r;
            if (row >= M) continue;
            ushort v = cvt_bf16(acc[ct][r] + bv_);
            if (which == 0) {
                Qb[row * 128 + col] = v;
            } else {
                KVu[row * 256 + (col >> 1) * 4 + (col & 1) + ((which == 2) ? 2 : 0)] = v;
            }
        }
    }
}

// Final projection: A bf16 [M,128] @ W^T + bias -> fp32 out
__global__ __launch_bounds__(256) void gemm_out(
    const ushort* __restrict__ A, const ushort* __restrict__ W,
    const float* __restrict__ bias, float* __restrict__ C, int M)
{
    const int lane = threadIdx.x & 63;
    const int wave = threadIdx.x >> 6;
    const int ml   = lane & 15;
    const int quad = lane >> 4;
    const int m0   = blockIdx.x * 64 + wave * 16;

    int arow = m0 + ml; if (arow >= M) arow = M - 1;
    const ushort* ap = A + arow * 128 + quad * 8;

    f32x4 acc[8];
#pragma unroll
    for (int ct = 0; ct < 8; ++ct) acc[ct] = (f32x4){0.f, 0.f, 0.f, 0.f};

#pragma unroll
    for (int ks = 0; ks < 128; ks += 32) {
        bf16x8 af = *reinterpret_cast<const bf16x8*>(ap + ks);
#pragma unroll
        for (int ct = 0; ct < 8; ++ct) {
            bf16x8 bf = *reinterpret_cast<const bf16x8*>(
                W + (ct * 16 + ml) * 128 + ks + quad * 8);
            acc[ct] = __builtin_amdgcn_mfma_f32_16x16x32_bf16(af, bf, acc[ct], 0, 0, 0);
        }
    }

#pragma unroll
    for (int ct = 0; ct < 8; ++ct) {
        int col = ct * 16 + ml;
        float bv_ = bias[col];
#pragma unroll
        for (int r = 0; r < 4; ++r) {
            int row = m0 + quad * 4 + r;
            if (row < M)
                C[row * 128 + col] = acc[ct][r] + bv_;
        }
    }
}

// ---------------------------------------------------------------------------
// Hierarchical exclusive scan (3 small kernels) + scatter (int2 {e, src}).
// ---------------------------------------------------------------------------
__global__ __launch_bounds__(256) void scan_blocks(
    const int* __restrict__ deg, int* __restrict__ excl, int* __restrict__ bsum)
{
    __shared__ int sh[256];
    int t = threadIdx.x;
    int gid = blockIdx.x * 256 + t;
    int v = (gid < N_NODES) ? deg[gid] : 0;
    sh[t] = v;
    __syncthreads();
#pragma unroll
    for (int off = 1; off < 256; off <<= 1) {
        int u = (t >= off) ? sh[t - off] : 0;
        __syncthreads();
        sh[t] += u;
        __syncthreads();
    }
    if (gid < N_NODES) excl[gid] = sh[t] - v;
    if (t == 255) bsum[blockIdx.x] = sh[255];
}

__global__ __launch_bounds__(128) void scan_tops(
    const int* __restrict__ bsum, int* __restrict__ bbase)
{
    __shared__ int sh[128];
    int t = threadIdx.x;
    int v = (t < NBLK) ? bsum[t] : 0;
    sh[t] = v;
    __syncthreads();
#pragma unroll
    for (int off = 1; off < 128; off <<= 1) {
        int u = (t >= off) ? sh[t - off] : 0;
        __syncthreads();
        sh[t] += u;
        __syncthreads();
    }
    if (t < NBLK) bbase[t] = sh[t] - v;
}

__global__ __launch_bounds__(256) void scan_apply(
    int* __restrict__ excl, const int* __restrict__ bbase,
    int* __restrict__ cursor)
{
    int t = threadIdx.x;
    int gid = blockIdx.x * 256 + t;
    if (gid < N_NODES) {
        int o = excl[gid] + bbase[blockIdx.x];
        excl[gid] = o;         // excl buffer IS offsets
        cursor[gid] = o;
    }
    if (blockIdx.x == 0 && t == 0) excl[N_NODES] = N_EDGES;
}

__global__ __launch_bounds__(256) void scatter_edges(
    const int* __restrict__ ei, int* __restrict__ cursor,
    int2* __restrict__ csr2)
{
    int e = blockIdx.x * 256 + threadIdx.x;
    if (e >= N_EDGES) return;
    int dst = ei[e];
    int src = ei[N_EDGES + e];
    int pos = atomicAdd(&cursor[dst], 1);
    csr2[pos] = make_int2(e, src);
}

// ---------------------------------------------------------------------------
// Fused attention v5. One wave per node; lane l holds dims {2l,2l+1};
// head h = l>>3. csr2 = {edge, src} pairs, contiguous per node: ONE coalesced
// preload per 64-edge batch, broadcast via __shfl. 4-edge unroll (8-unroll
// regressed: compiler serialized loads to cap VGPR). One uint2 KV load/edge.
// exp without max-subtraction (identical softmax; logits are O(+-10)).
// ---------------------------------------------------------------------------
__global__ __launch_bounds__(256) void fused_attn(
    const ushort* __restrict__ Q2, const uint2* __restrict__ KV,
    const float* __restrict__ attn_bias,
    const int* __restrict__ offsets, const int2* __restrict__ csr2,
    float* __restrict__ logits, ushort* __restrict__ AGG)
{
    const int lane = threadIdx.x & 63;
    const int wid  = threadIdx.x >> 6;
    const int n = blockIdx.x * 4 + wid;
    const int start = offsets[n], end = offsets[n + 1];
    const int h = lane >> 3;

    uint qu = reinterpret_cast<const uint*>(Q2)[n * 64 + lane];
    float qx = bf16_lo(qu), qy = bf16_hi(qu);

    float z = 0.f, accx = 0.f, accy = 0.f;

    for (int base = start; base < end; base += 64) {
        int cnt = end - base; if (cnt > 64) cnt = 64;
        int e_l = 0, s_l = 0;
        if (lane < cnt) {
            int2 es = csr2[base + lane];
            e_l = es.x; s_l = es.y;
        }
        int j = 0;
        for (; j + 3 < cnt; j += 4) {
            int e0 = __shfl(e_l, j, 64),     e1 = __shfl(e_l, j + 1, 64);
            int e2 = __shfl(e_l, j + 2, 64), e3 = __shfl(e_l, j + 3, 64);
            int s0 = __shfl(s_l, j, 64),     s1 = __shfl(s_l, j + 1, 64);
            int s2 = __shfl(s_l, j + 2, 64), s3 = __shfl(s_l, j + 3, 64);
            uint2 kv0 = KV[s0 * 64 + lane], kv1 = KV[s1 * 64 + lane];
            uint2 kv2 = KV[s2 * 64 + lane], kv3 = KV[s3 * 64 + lane];
            float b0 = attn_bias[e0 * 8 + h], b1 = attn_bias[e1 * 8 + h];
            float b2 = attn_bias[e2 * 8 + h], b3 = attn_bias[e3 * 8 + h];

            float d0 = qx * bf16_lo(kv0.x) + qy * bf16_hi(kv0.x);
            float d1 = qx * bf16_lo(kv1.x) + qy * bf16_hi(kv1.x);
            float d2 = qx * bf16_lo(kv2.x) + qy * bf16_hi(kv2.x);
            float d3 = qx * bf16_lo(kv3.x) + qy * bf16_hi(kv3.x);
#pragma unroll
            for (int off = 1; off < 8; off <<= 1) {
                d0 += __shfl_xor(d0, off, 64);
                d1 += __shfl_xor(d1, off, 64);
                d2 += __shfl_xor(d2, off, 64);
                d3 += __shfl_xor(d3, off, 64);
            }
            float l0 = 0.25f * d0 + b0, l1 = 0.25f * d1 + b1;
            float l2 = 0.25f * d2 + b2, l3 = 0.25f * d3 + b3;
            if ((lane & 7) == 0) {
                logits[e0 * 8 + h] = l0;
                logits[e1 * 8 + h] = l1;
                logits[e2 * 8 + h] = l2;
                logits[e3 * 8 + h] = l3;
            }
            float p0 = __expf(l0), p1 = __expf(l1);
            float p2 = __expf(l2), p3 = __expf(l3);
            z += (p0 + p1) + (p2 + p3);
            accx += p0 * bf16_lo(kv0.y) + p1 * bf16_lo(kv1.y)
                  + p2 * bf16_lo(kv2.y) + p3 * bf16_lo(kv3.y);
            accy += p0 * bf16_hi(kv0.y) + p1 * bf16_hi(kv1.y)
                  + p2 * bf16_hi(kv2.y) + p3 * bf16_hi(kv3.y);
        }
        for (; j < cnt; ++j) {
            int e0 = __shfl(e_l, j, 64);
            int s0 = __shfl(s_l, j, 64);
            uint2 kv0 = KV[s0 * 64 + lane];
            float b0 = attn_bias[e0 * 8 + h];
            float d0 = qx * bf16_lo(kv0.x) + qy * bf16_hi(kv0.x);
#pragma unroll
            for (int off = 1; off < 8; off <<= 1) d0 += __shfl_xor(d0, off, 64);
            float l0 = 0.25f * d0 + b0;
            if ((lane & 7) == 0) logits[e0 * 8 + h] = l0;
            float p0 = __expf(l0);
            z += p0;
            accx += p0 * bf16_lo(kv0.y);
            accy += p0 * bf16_hi(kv0.y);
        }
    }

    float inv = (z > 0.f) ? 1.f / z : 0.f;
    reinterpret_cast<uint*>(AGG)[n * 64 + lane] = pack2_bf16(accx * inv, accy * inv);
}

// ---------------------------------------------------------------------------
extern "C" void kernel_launch(void* const* d_in, const int* in_sizes, int n_in,
                              void* d_out, int out_size, void* d_ws, size_t ws_size,
                              hipStream_t stream)
{
    const float* x         = (const float*)d_in[0];
    const int*   ei        = (const int*)  d_in[1];
    const float* attn_bias = (const float*)d_in[2];
    const float* Wq = (const float*)d_in[3];
    const float* bq = (const float*)d_in[4];
    const float* Wk = (const float*)d_in[5];
    const float* bk = (const float*)d_in[6];
    const float* Wv = (const float*)d_in[7];
    const float* bv = (const float*)d_in[8];
    const float* Wo = (const float*)d_in[9];
    const float* bo = (const float*)d_in[10];

    float* out    = (float*)d_out;                // [N,128]
    float* logits = out + N_NODES * EMBED;        // [E,8] (output 1)

    ushort* xb   = (ushort*)d_ws;                 // N*128
    ushort* wb   = xb + NX;                       // 4*16384 (Wq,Wk,Wv,Wo)
    ushort* Qb   = wb + 4 * 16384;                // N*128
    ushort* KVu  = Qb + NX;                       // N*256 (K/V interleaved)
    ushort* AGGb = KVu + 2 * NX;                  // N*128
    int* deg     = (int*)(AGGb + NX);
    int* offsets = deg + N_NODES;                 // N+1 (also excl buffer)
    int* cursor  = offsets + N_NODES + 1;
    int2* csr2   = (int2*)(cursor + N_NODES);     // E pairs {edge, src}
    int* bsum    = (int*)(csr2 + N_EDGES);        // NBLK
    int* bbase   = bsum + NBLK;                   // NBLK

    int npairs = (NX + 4 * 16384) / 2;
    convert_all<<<(npairs + 255) / 256, 256, 0, stream>>>(x, Wq, Wk, Wv, Wo, xb, wb, deg);

    int gblocks = (N_NODES + 63) / 64;            // 391
    dim3 qkvgrid(gblocks, 4);                     // y=0..2 gemm, y=3 histogram
    gemm_qkv_deg<<<qkvgrid, 256, 0, stream>>>(xb, wb, bq, bk, bv, Qb, KVu,
                                              ei, deg, N_NODES);

    scan_blocks<<<NBLK, 256, 0, stream>>>(deg, offsets, bsum);
    scan_tops<<<1, 128, 0, stream>>>(bsum, bbase);
    scan_apply<<<NBLK, 256, 0, stream>>>(offsets, bbase, cursor);
    scatter_edges<<<(N_EDGES + 255) / 256, 256, 0, stream>>>(ei, cursor, csr2);

    fused_attn<<<N_NODES / 4, 256, 0, stream>>>(Qb, (const uint2*)KVu, attn_bias,
                                                offsets, csr2, logits, AGGb);

    gemm_out<<<gblocks, 256, 0, stream>>>(AGGb, wb + 3 * 16384, bo, out, N_NODES);
}